// Round 1
// baseline (374.706 us; speedup 1.0000x reference)
//
#include <hip/hip_runtime.h>

// DIN attention: B=4096, L=100, D=64
// Factorized: h[b,l] = k @ M_b + cu_b, M_b[i][j] = V[i][j] + c_i*T[i][j]
//   V = W1[64:128]-W1[128:192], T = W1[192:256], cu = c@(W1[0:64]+W1[128:192]) + b1
//
// ws layout (floats):
//   [0,1024):    stat buckets [8][128] (sum[0:64], sumsq[64:128]) — zeroed each launch
//   [1024,1088): mu
//   [1088,1152): rsig = rsqrt(var + 1e-9)

constexpr int Bn = 4096;
constexpr int Ln = 100;
constexpr int Dn = 64;
constexpr float kEps = 1e-9f;

template <int PHASE>
__global__ __launch_bounds__(256) void din_kernel(
    const float* __restrict__ cand, const float* __restrict__ clicks,
    const int* __restrict__ mask, const float* __restrict__ W1,
    const float* __restrict__ b1, const float* __restrict__ alpha,
    const float* __restrict__ W2, const float* __restrict__ b2,
    float* __restrict__ ws, float* __restrict__ out) {
  constexpr int KROWS = (PHASE == 0) ? 4 : Ln;
  __shared__ alignas(16) float Ms[64][64];      // M_b[i][j]
  __shared__ alignas(16) float kls[KROWS][64];  // click rows (broadcast source)
  __shared__ float csh[64];
  __shared__ float cu[64];
  __shared__ float part[4][64];
  __shared__ float part2[4][64];
  __shared__ float s_lds[Ln];   // row logits (PHASE1)
  __shared__ float w_lds[Ln];   // softmax weights (PHASE1)

  const int b = blockIdx.x;
  const int tid = threadIdx.x;
  const int lane = tid & 63;
  const int w = tid >> 6;

  if (tid < 64) csh[tid] = cand[(size_t)b * 64 + tid];
  __syncthreads();

  // Build M_b in LDS: M[i][j] = W1[(64+i)*64+j] - W1[(128+i)*64+j] + c_i*W1[(192+i)*64+j]
#pragma unroll
  for (int r = 0; r < 16; ++r) {
    int idx = r * 256 + tid;
    int i = idx >> 6, j = idx & 63;
    Ms[i][j] = W1[(64 + i) * 64 + j] - W1[(128 + i) * 64 + j] +
               csh[i] * W1[(192 + i) * 64 + j];
  }
  // cu partials: wave w covers i in [16w, 16w+16)
  {
    float p = 0.f;
#pragma unroll
    for (int r = 0; r < 16; ++r) {
      int i = w * 16 + r;
      p = fmaf(csh[i], W1[i * 64 + lane] + W1[(128 + i) * 64 + lane], p);
    }
    part[w][lane] = p;
  }
  __syncthreads();
  if (tid < 64)
    cu[tid] = b1[tid] + part[0][tid] + part[1][tid] + part[2][tid] + part[3][tid];
  __syncthreads();

  // Lane j holds column j of M in registers
  float Mreg[64];
#pragma unroll
  for (int i = 0; i < 64; ++i) Mreg[i] = Ms[i][lane];
  const float cu_j = cu[lane];

  float mu_j = 0.f, rs_j = 0.f, a_j = 0.f, w2_j = 0.f, b2v = 0.f;
  if (PHASE == 1) {
    mu_j = ws[1024 + lane];
    rs_j = ws[1088 + lane];
    a_j = alpha[lane];
    w2_j = W2[lane];
    b2v = b2[0];
  }

  float ssum = 0.f, ssq = 0.f;
  const float* crow = clicks + (size_t)b * Ln * 64;

  for (int t = 0; t < 25; ++t) {
    const int l = w + 4 * t;
    const int slot = (PHASE == 0) ? w : l;
    kls[slot][lane] = crow[(size_t)l * 64 + lane];
    // wave-local LDS RAW; compiler inserts lgkmcnt wait
    float acc = cu_j;
    const float4* kvec = (const float4*)kls[slot];
#pragma unroll
    for (int i4 = 0; i4 < 16; ++i4) {
      float4 kk = kvec[i4];  // wave-uniform address -> LDS broadcast
      acc = fmaf(kk.x, Mreg[4 * i4 + 0], acc);
      acc = fmaf(kk.y, Mreg[4 * i4 + 1], acc);
      acc = fmaf(kk.z, Mreg[4 * i4 + 2], acc);
      acc = fmaf(kk.w, Mreg[4 * i4 + 3], acc);
    }
    if (PHASE == 0) {
      ssum += acc;
      ssq = fmaf(acc, acc, ssq);
    } else {
      float hn = (acc - mu_j) * rs_j;
      float p = 1.f / (1.f + __expf(-hn));
      float dj = acc * fmaf(p, 1.f - a_j, a_j);
      float sv = dj * w2_j;
#pragma unroll
      for (int off = 32; off >= 1; off >>= 1) sv += __shfl_xor(sv, off);
      if (lane == 0) s_lds[l] = sv + b2v;
    }
  }

  if (PHASE == 0) {
    part[w][lane] = ssum;
    part2[w][lane] = ssq;
    __syncthreads();
    if (w == 0) {
      float s = part[0][lane] + part[1][lane] + part[2][lane] + part[3][lane];
      atomicAdd(&ws[(b & 7) * 128 + lane], s);
    } else if (w == 1) {
      float s = part2[0][lane] + part2[1][lane] + part2[2][lane] + part2[3][lane];
      atomicAdd(&ws[(b & 7) * 128 + 64 + lane], s);
    }
  } else {
    __syncthreads();
    // Masked softmax over L=100, done by wave 0 (lane covers l=lane and l=lane+64)
    if (w == 0) {
      const int* mrow = mask + (size_t)b * Ln;
      const bool has1 = (lane + 64) < Ln;
      float v0 = s_lds[lane];
      int m0 = mrow[lane];
      float v1 = has1 ? s_lds[lane + 64] : 0.f;
      int m1 = has1 ? mrow[lane + 64] : 0;
      float x0 = m0 ? v0 : -3.0e38f;
      float x1 = m1 ? v1 : -3.0e38f;
      float mx = fmaxf(x0, x1);
#pragma unroll
      for (int off = 32; off >= 1; off >>= 1) mx = fmaxf(mx, __shfl_xor(mx, off));
      float e0 = m0 ? __expf(v0 - mx) : 0.f;
      float e1 = m1 ? __expf(v1 - mx) : 0.f;
      float se = e0 + e1;
#pragma unroll
      for (int off = 32; off >= 1; off >>= 1) se += __shfl_xor(se, off);
      float inv = 1.f / se;
      w_lds[lane] = e0 * inv;
      if (has1) w_lds[lane + 64] = e1 * inv;
    }
    __syncthreads();
    // out[b][j] = sum_l w_l * clicks[b][l][j] (click rows cached in LDS)
    float acc = 0.f;
#pragma unroll
    for (int t = 0; t < 25; ++t) {
      int l = w + 4 * t;
      acc = fmaf(w_lds[l], kls[l][lane], acc);
    }
    part[w][lane] = acc;
    __syncthreads();
    if (w == 0)
      out[(size_t)b * 64 + lane] =
          part[0][lane] + part[1][lane] + part[2][lane] + part[3][lane];
  }
}

__global__ void finalize_stats(float* __restrict__ ws) {
  int j = threadIdx.x;  // 64 threads
  float s = 0.f, q = 0.f;
#pragma unroll
  for (int k = 0; k < 8; ++k) {
    s += ws[k * 128 + j];
    q += ws[k * 128 + 64 + j];
  }
  const float n = (float)(Bn * Ln);
  float mu = s / n;
  float var = q / n - mu * mu;
  ws[1024 + j] = mu;
  ws[1088 + j] = rsqrtf(var + kEps);
}

extern "C" void kernel_launch(void* const* d_in, const int* in_sizes, int n_in,
                              void* d_out, int out_size, void* d_ws,
                              size_t ws_size, hipStream_t stream) {
  const float* cand = (const float*)d_in[0];
  const float* clicks = (const float*)d_in[1];
  const int* mask = (const int*)d_in[2];
  const float* W1 = (const float*)d_in[3];
  const float* b1 = (const float*)d_in[4];
  const float* alpha = (const float*)d_in[5];
  const float* W2 = (const float*)d_in[6];
  const float* b2 = (const float*)d_in[7];
  float* out = (float*)d_out;
  float* ws = (float*)d_ws;

  hipMemsetAsync(d_ws, 0, 1024 * sizeof(float), stream);
  din_kernel<0><<<Bn, 256, 0, stream>>>(cand, clicks, mask, W1, b1, alpha, W2,
                                        b2, ws, out);
  finalize_stats<<<1, 64, 0, stream>>>(ws);
  din_kernel<1><<<Bn, 256, 0, stream>>>(cand, clicks, mask, W1, b1, alpha, W2,
                                        b2, ws, out);
}

// Round 2
// 321.105 us; speedup vs baseline: 1.1669x; 1.1669x over previous
//
#include <hip/hip_runtime.h>

// DIN attention: B=4096, L=100, D=64
// Factorized: h[b,l] = k @ M_b + cu_b, M_b[i][j] = V[i][j] + c_i*T[i][j]
//   V = W1[64:128]-W1[128:192], T = W1[192:256], cu = c@(W1[0:64]+W1[128:192]) + b1
//
// ws layout (floats):
//   [0,2048):    stat buckets [16][128] (sum[0:64], sumsq[64:128]) — zeroed each launch
//   [2048,2112): mu
//   [2112,2176): rsig = rsqrt(var + 1e-9)

constexpr int Bn = 4096;
constexpr int Ln = 100;
constexpr float kEps = 1e-9f;
constexpr int NBUCK = 16;

template <int PHASE>
__global__ __launch_bounds__(256) void din_kernel(
    const float* __restrict__ cand, const float* __restrict__ clicks,
    const int* __restrict__ mask, const float* __restrict__ W1,
    const float* __restrict__ b1, const float* __restrict__ alpha,
    const float* __restrict__ W2, const float* __restrict__ b2,
    float* __restrict__ ws, float* __restrict__ out) {
  // smem is Ms[64][64] during the prologue; rows 0..7 are reused as the
  // per-wave double-buffered click-row broadcast slots in the main loop.
  __shared__ alignas(16) float smem[64][64];
  __shared__ float csh[64];
  __shared__ float cu[64];
  __shared__ float part[4][64];
  __shared__ float part2[4][64];
  __shared__ float s_lds[Ln];   // row logits (PHASE1)
  __shared__ float w_lds[Ln];   // softmax weights (PHASE1)

  const int b = blockIdx.x;
  const int tid = threadIdx.x;
  const int lane = tid & 63;
  const int w = tid >> 6;

  if (tid < 64) csh[tid] = cand[(size_t)b * 64 + tid];
  __syncthreads();

  // Build M_b in LDS: M[i][j] = W1[(64+i)*64+j] - W1[(128+i)*64+j] + c_i*W1[(192+i)*64+j]
#pragma unroll
  for (int r = 0; r < 16; ++r) {
    int idx = r * 256 + tid;
    int i = idx >> 6, j = idx & 63;
    smem[i][j] = W1[(64 + i) * 64 + j] - W1[(128 + i) * 64 + j] +
                 csh[i] * W1[(192 + i) * 64 + j];
  }
  // cu partials: wave w covers i in [16w, 16w+16)
  {
    float p = 0.f;
#pragma unroll
    for (int r = 0; r < 16; ++r) {
      int i = w * 16 + r;
      p = fmaf(csh[i], W1[i * 64 + lane] + W1[(128 + i) * 64 + lane], p);
    }
    part[w][lane] = p;
  }
  __syncthreads();
  if (tid < 64)
    cu[tid] = b1[tid] + part[0][tid] + part[1][tid] + part[2][tid] + part[3][tid];
  __syncthreads();

  // Lane j holds column j of M in registers
  float Mreg[64];
#pragma unroll
  for (int i = 0; i < 64; ++i) Mreg[i] = smem[i][lane];
  const float cu_j = cu[lane];
  __syncthreads();  // all waves done reading Ms before rows 0..7 are reused

  float mu_j = 0.f, rs_j = 0.f, a_j = 0.f, w2_j = 0.f, b2v = 0.f;
  if (PHASE == 1) {
    mu_j = ws[2048 + lane];
    rs_j = ws[2112 + lane];
    a_j = alpha[lane];
    w2_j = W2[lane];
    b2v = b2[0];
  }

  float ssum = 0.f, ssq = 0.f;
  const float* crow = clicks + (size_t)b * Ln * 64;

  // Depth-2 prefetch of this wave's rows (l = w + 4t)
  float nxtA = crow[(size_t)w * 64 + lane];
  float nxtB = crow[(size_t)(w + 4) * 64 + lane];

  for (int t = 0; t < 25; ++t) {
    const int l = w + 4 * t;
    const int slot = w * 2 + (t & 1);
    smem[slot][lane] = nxtA;  // wave-local ds_write; no barrier needed
    nxtA = nxtB;
    if (t + 2 < 25) nxtB = crow[(size_t)(l + 8) * 64 + lane];

    float acc0 = 0.f, acc1 = 0.f, acc2 = 0.f, acc3 = 0.f;
    const float4* kvec = (const float4*)smem[slot];
#pragma unroll
    for (int i4 = 0; i4 < 16; ++i4) {
      float4 kk = kvec[i4];  // wave-uniform address -> LDS broadcast
      acc0 = fmaf(kk.x, Mreg[4 * i4 + 0], acc0);
      acc1 = fmaf(kk.y, Mreg[4 * i4 + 1], acc1);
      acc2 = fmaf(kk.z, Mreg[4 * i4 + 2], acc2);
      acc3 = fmaf(kk.w, Mreg[4 * i4 + 3], acc3);
    }
    float acc = cu_j + ((acc0 + acc1) + (acc2 + acc3));

    if (PHASE == 0) {
      ssum += acc;
      ssq = fmaf(acc, acc, ssq);
    } else {
      float hn = (acc - mu_j) * rs_j;
      float p = 1.f / (1.f + __expf(-hn));
      float dj = acc * fmaf(p, 1.f - a_j, a_j);
      float sv = dj * w2_j;
#pragma unroll
      for (int off = 32; off >= 1; off >>= 1) sv += __shfl_xor(sv, off);
      if (lane == 0) s_lds[l] = sv + b2v;
    }
  }

  if (PHASE == 0) {
    part[w][lane] = ssum;
    part2[w][lane] = ssq;
    __syncthreads();
    if (w == 0) {
      float s = part[0][lane] + part[1][lane] + part[2][lane] + part[3][lane];
      atomicAdd(&ws[(b & (NBUCK - 1)) * 128 + lane], s);
    } else if (w == 1) {
      float s = part2[0][lane] + part2[1][lane] + part2[2][lane] + part2[3][lane];
      atomicAdd(&ws[(b & (NBUCK - 1)) * 128 + 64 + lane], s);
    }
  } else {
    __syncthreads();
    // Masked softmax over L=100, done by wave 0 (lane covers l=lane and l=lane+64)
    if (w == 0) {
      const int* mrow = mask + (size_t)b * Ln;
      const bool has1 = (lane + 64) < Ln;
      float v0 = s_lds[lane];
      int m0 = mrow[lane];
      float v1 = has1 ? s_lds[lane + 64] : 0.f;
      int m1 = has1 ? mrow[lane + 64] : 0;
      float x0 = m0 ? v0 : -3.0e38f;
      float x1 = m1 ? v1 : -3.0e38f;
      float mx = fmaxf(x0, x1);
#pragma unroll
      for (int off = 32; off >= 1; off >>= 1) mx = fmaxf(mx, __shfl_xor(mx, off));
      float e0 = m0 ? __expf(v0 - mx) : 0.f;
      float e1 = m1 ? __expf(v1 - mx) : 0.f;
      float se = e0 + e1;
#pragma unroll
      for (int off = 32; off >= 1; off >>= 1) se += __shfl_xor(se, off);
      float inv = 1.f / se;
      w_lds[lane] = e0 * inv;
      if (has1) w_lds[lane + 64] = e1 * inv;
    }
    __syncthreads();
    // out[b][j] = sum_l w_l * clicks[b][l][j]; rows re-read from L2/L3
    float acc = 0.f;
#pragma unroll 5
    for (int t = 0; t < 25; ++t) {
      int l = w + 4 * t;
      acc = fmaf(w_lds[l], crow[(size_t)l * 64 + lane], acc);
    }
    part[w][lane] = acc;
    __syncthreads();
    if (w == 0)
      out[(size_t)b * 64 + lane] =
          part[0][lane] + part[1][lane] + part[2][lane] + part[3][lane];
  }
}

__global__ void finalize_stats(float* __restrict__ ws) {
  int j = threadIdx.x;  // 64 threads
  float s = 0.f, q = 0.f;
#pragma unroll
  for (int k = 0; k < NBUCK; ++k) {
    s += ws[k * 128 + j];
    q += ws[k * 128 + 64 + j];
  }
  const float n = (float)(Bn * Ln);
  float mu = s / n;
  float var = q / n - mu * mu;
  ws[2048 + j] = mu;
  ws[2112 + j] = rsqrtf(var + kEps);
}

extern "C" void kernel_launch(void* const* d_in, const int* in_sizes, int n_in,
                              void* d_out, int out_size, void* d_ws,
                              size_t ws_size, hipStream_t stream) {
  const float* cand = (const float*)d_in[0];
  const float* clicks = (const float*)d_in[1];
  const int* mask = (const int*)d_in[2];
  const float* W1 = (const float*)d_in[3];
  const float* b1 = (const float*)d_in[4];
  const float* alpha = (const float*)d_in[5];
  const float* W2 = (const float*)d_in[6];
  const float* b2 = (const float*)d_in[7];
  float* out = (float*)d_out;
  float* ws = (float*)d_ws;

  hipMemsetAsync(d_ws, 0, NBUCK * 128 * sizeof(float), stream);
  din_kernel<0><<<Bn, 256, 0, stream>>>(cand, clicks, mask, W1, b1, alpha, W2,
                                        b2, ws, out);
  finalize_stats<<<1, 64, 0, stream>>>(ws);
  din_kernel<1><<<Bn, 256, 0, stream>>>(cand, clicks, mask, W1, b1, alpha, W2,
                                        b2, ws, out);
}

// Round 4
// 308.849 us; speedup vs baseline: 1.2132x; 1.0397x over previous
//
#include <hip/hip_runtime.h>

// DIN attention: B=4096, L=100, D=64 — MFMA (bf16 3-term split) version.
// Factorized: h[b,l] = k_l @ M_b + cu_b, M_b[i][j] = V[i][j] + c_i*T[i][j]
//   V = W1[64:128]-W1[128:192], T = W1[192:256], cu = c@(W1[0:64]+W1[128:192]) + b1
// Split: k = kh + kl, M = Mh + Ml (bf16 each);
//   h ~= kh@Mh + kh@Ml + kl@Mh   (error ~2^-16 — fp32-grade)
// Per block: C[112x64] (rows 100..111 zero-padded) = A[112x192] @ B[192x64]
// via mfma_f32_16x16x32_bf16; wave w owns col-tile w (cols 16w..16w+15).
//
// ws layout (floats):
//   [0,2048):    stat buckets [16][128] (sum[0:64], sumsq[64:128]) — zeroed each launch
//   [2048,2112): mu
//   [2112,2176): rsig = rsqrt(var + 1e-9)

constexpr int Bn = 4096;
constexpr int Ln = 100;
constexpr int LP = 112;  // padded rows (7 tiles of 16)
constexpr float kEps = 1e-9f;
constexpr int NBUCK = 16;

typedef __attribute__((ext_vector_type(8))) short short8v;
typedef __attribute__((ext_vector_type(4))) float f32x4;

static __device__ __forceinline__ unsigned short f2bf(float f) {
  unsigned u = __float_as_uint(f);
  return (unsigned short)((u + 0x7FFFu + ((u >> 16) & 1u)) >> 16);
}
static __device__ __forceinline__ float bf2f(unsigned short h) {
  return __uint_as_float(((unsigned)h) << 16);
}
// Row-major bf16 tile, row stride 128B, XOR-swizzled (G4: breaks the
// 16-way conflict of stride-128B column reads). Same fn for write+read.
static __device__ __forceinline__ int swz(int row, int byteInRow) {
  return row * 128 + (byteInRow ^ ((row & 7) << 4));
}

template <int PHASE>
__global__ __launch_bounds__(256) void din_kernel(
    const float* __restrict__ cand, const float* __restrict__ clicks,
    const int* __restrict__ mask, const float* __restrict__ W1,
    const float* __restrict__ b1, const float* __restrict__ alpha,
    const float* __restrict__ W2, const float* __restrict__ b2,
    float* __restrict__ ws, float* __restrict__ out) {
  __shared__ alignas(16) unsigned short AhS[LP * 64];  // kh, swizzled rows
  __shared__ alignas(16) unsigned short AlS[LP * 64];  // kl
  __shared__ alignas(16) unsigned short MhS[64 * 64];  // Mh^T [j][i], swizzled
  __shared__ alignas(16) unsigned short MlS[64 * 64];  // Ml^T
  __shared__ float cshS[64];
  __shared__ float cuS[64];
  __shared__ float partS[4][64];
  __shared__ float svp[4][LP];
  __shared__ float s_lds[LP];
  __shared__ float w_lds[LP];

  const int b = blockIdx.x;
  const int tid = threadIdx.x;
  const int lane = tid & 63;
  const int w = tid >> 6;

  if (tid < 64) cshS[tid] = cand[(size_t)b * 64 + tid];
  __syncthreads();

  // ---- Prologue A: build M^T (split) + cu partials. thread: col j=lane,
  // i in [16w,16w+16) as 8 pairs (pack 2 bf16 per b32 write).
  {
    float cuacc = 0.f;
#pragma unroll
    for (int p = 0; p < 8; ++p) {
      const int i0 = w * 16 + p * 2;
      float m[2];
#pragma unroll
      for (int q = 0; q < 2; ++q) {
        const int i = i0 + q;
        const float ci = cshS[i];
        m[q] = W1[(64 + i) * 64 + lane] - W1[(128 + i) * 64 + lane] +
               ci * W1[(192 + i) * 64 + lane];
        cuacc = fmaf(ci, W1[i * 64 + lane] + W1[(128 + i) * 64 + lane], cuacc);
      }
      unsigned short h0 = f2bf(m[0]), h1 = f2bf(m[1]);
      unsigned short l0 = f2bf(m[0] - bf2f(h0)), l1 = f2bf(m[1] - bf2f(h1));
      *(unsigned*)((char*)MhS + swz(lane, i0 * 2)) =
          (unsigned)h0 | ((unsigned)h1 << 16);
      *(unsigned*)((char*)MlS + swz(lane, i0 * 2)) =
          (unsigned)l0 | ((unsigned)l1 << 16);
    }
    partS[w][lane] = cuacc;
  }

  // ---- Prologue B: clicks -> bf16 split in LDS. Wave w: rows [28w,28w+28),
  // 2 rows/iter: lane covers (row = lane>>5, col pair = lane&31).
  {
    const float2* crow2 = (const float2*)(clicks + (size_t)b * Ln * 64);
    const int colh = lane & 31;
    const int rsel = lane >> 5;
#pragma unroll
    for (int it = 0; it < 14; ++it) {
      const int l = 28 * w + it * 2 + rsel;
      float v0 = 0.f, v1 = 0.f;
      if (l < Ln) {
        float2 v = crow2[l * 32 + colh];
        v0 = v.x;
        v1 = v.y;
      }
      unsigned short h0 = f2bf(v0), h1 = f2bf(v1);
      unsigned short q0 = f2bf(v0 - bf2f(h0)), q1 = f2bf(v1 - bf2f(h1));
      *(unsigned*)((char*)AhS + swz(l, colh * 4)) =
          (unsigned)h0 | ((unsigned)h1 << 16);
      *(unsigned*)((char*)AlS + swz(l, colh * 4)) =
          (unsigned)q0 | ((unsigned)q1 << 16);
    }
  }
  __syncthreads();
  if (tid < 64)
    cuS[tid] =
        b1[tid] + partS[0][tid] + partS[1][tid] + partS[2][tid] + partS[3][tid];
  __syncthreads();

  // ---- MFMA phase. Wave w = col-tile w. Lane roles (16x16x32 bf16):
  //   A: row = lane&15, k = (lane>>4)*8 + e ;  B: col = lane&15, same k
  //   D: col = lane&15, row = (lane>>4)*4 + r   [m89-verified]
  const int lo4 = lane & 15;
  const int hi2 = lane >> 4;
  const int bk2 = hi2 * 16;  // byte offset of this lane's 8-elem k chunk
  const int bcol = w * 16 + lo4;

  short8v Bh0 = *(const short8v*)((char*)MhS + swz(bcol, bk2));
  short8v Bh1 = *(const short8v*)((char*)MhS + swz(bcol, 64 + bk2));
  short8v Bl0 = *(const short8v*)((char*)MlS + swz(bcol, bk2));
  short8v Bl1 = *(const short8v*)((char*)MlS + swz(bcol, 64 + bk2));

  f32x4 acc[7];
#pragma unroll
  for (int rt = 0; rt < 7; ++rt) acc[rt] = (f32x4){0.f, 0.f, 0.f, 0.f};

#pragma unroll
  for (int rt = 0; rt < 7; ++rt) {
    const int arow = rt * 16 + lo4;
    short8v Ah0 = *(const short8v*)((char*)AhS + swz(arow, bk2));
    short8v Ah1 = *(const short8v*)((char*)AhS + swz(arow, 64 + bk2));
    short8v Al0 = *(const short8v*)((char*)AlS + swz(arow, bk2));
    short8v Al1 = *(const short8v*)((char*)AlS + swz(arow, 64 + bk2));
    f32x4 a = acc[rt];
    a = __builtin_amdgcn_mfma_f32_16x16x32_bf16(Ah0, Bh0, a, 0, 0, 0);
    a = __builtin_amdgcn_mfma_f32_16x16x32_bf16(Ah1, Bh1, a, 0, 0, 0);
    a = __builtin_amdgcn_mfma_f32_16x16x32_bf16(Ah0, Bl0, a, 0, 0, 0);
    a = __builtin_amdgcn_mfma_f32_16x16x32_bf16(Ah1, Bl1, a, 0, 0, 0);
    a = __builtin_amdgcn_mfma_f32_16x16x32_bf16(Al0, Bh0, a, 0, 0, 0);
    a = __builtin_amdgcn_mfma_f32_16x16x32_bf16(Al1, Bh1, a, 0, 0, 0);
    acc[rt] = a;
  }

  const int j = w * 16 + lo4;  // this lane's output column
  const float cuj = cuS[j];

  if (PHASE == 0) {
    // ---- Stats: column sums of h and h^2 over l<100.
    float ssum = 0.f, ssq = 0.f;
#pragma unroll
    for (int rt = 0; rt < 7; ++rt) {
#pragma unroll
      for (int r = 0; r < 4; ++r) {
        const int l = rt * 16 + hi2 * 4 + r;
        const float h = acc[rt][r] + cuj;
        if (l < Ln) {
          ssum += h;
          ssq = fmaf(h, h, ssq);
        }
      }
    }
    ssum += __shfl_xor(ssum, 16);
    ssum += __shfl_xor(ssum, 32);
    ssq += __shfl_xor(ssq, 16);
    ssq += __shfl_xor(ssq, 32);
    if (hi2 == 0) {
      atomicAdd(&ws[(b & (NBUCK - 1)) * 128 + j], ssum);
      atomicAdd(&ws[(b & (NBUCK - 1)) * 128 + 64 + j], ssq);
    }
  } else {
    // ---- Dice + logits.
    const float muj = ws[2048 + j];
    const float rsj = ws[2112 + j];
    const float aj = alpha[j];
    const float w2j = W2[j];
    const float b2v = b2[0];
#pragma unroll
    for (int rt = 0; rt < 7; ++rt) {
#pragma unroll
      for (int r = 0; r < 4; ++r) {
        const int l = rt * 16 + hi2 * 4 + r;
        const float h = acc[rt][r] + cuj;
        const float hn = (h - muj) * rsj;
        const float p = 1.f / (1.f + __expf(-hn));
        const float d = h * fmaf(p, 1.f - aj, aj);
        float sv = d * w2j;  // partial over this wave's 16 cols
        sv += __shfl_xor(sv, 1);
        sv += __shfl_xor(sv, 2);
        sv += __shfl_xor(sv, 4);
        sv += __shfl_xor(sv, 8);
        if (lo4 == 0) svp[w][l] = sv;
      }
    }
    __syncthreads();
    if (tid < LP)
      s_lds[tid] = b2v + svp[0][tid] + svp[1][tid] + svp[2][tid] + svp[3][tid];
    __syncthreads();

    // ---- Masked softmax over L=100 (wave 0).
    if (w == 0) {
      const int* mrow = mask + (size_t)b * Ln;
      const bool has1 = (lane + 64) < Ln;
      float v0 = s_lds[lane];
      int m0 = mrow[lane];
      float v1 = has1 ? s_lds[lane + 64] : 0.f;
      int m1 = has1 ? mrow[lane + 64] : 0;
      float x0 = m0 ? v0 : -3.0e38f;
      float x1 = m1 ? v1 : -3.0e38f;
      float mx = fmaxf(x0, x1);
#pragma unroll
      for (int off = 32; off >= 1; off >>= 1) mx = fmaxf(mx, __shfl_xor(mx, off));
      float e0 = m0 ? __expf(v0 - mx) : 0.f;
      float e1 = m1 ? __expf(v1 - mx) : 0.f;
      float se = e0 + e1;
#pragma unroll
      for (int off = 32; off >= 1; off >>= 1) se += __shfl_xor(se, off);
      float inv = 1.f / se;
      w_lds[lane] = e0 * inv;
      if (has1) w_lds[lane + 64] = e1 * inv;
    }
    __syncthreads();

    // ---- out[b][j] = sum_l w_l * k[l][j], k reconstructed from kh+kl in LDS.
    float acco = 0.f;
#pragma unroll
    for (int t = 0; t < 25; ++t) {
      const int l = w + 4 * t;
      const float wl = w_lds[l];
      unsigned short kh = *(const unsigned short*)((char*)AhS + swz(l, lane * 2));
      unsigned short kl = *(const unsigned short*)((char*)AlS + swz(l, lane * 2));
      acco = fmaf(wl, bf2f(kh) + bf2f(kl), acco);
    }
    partS[w][lane] = acco;
    __syncthreads();
    if (w == 0)
      out[(size_t)b * 64 + lane] =
          partS[0][lane] + partS[1][lane] + partS[2][lane] + partS[3][lane];
  }
}

__global__ void finalize_stats(float* __restrict__ ws) {
  int j = threadIdx.x;  // 64 threads
  float s = 0.f, q = 0.f;
#pragma unroll
  for (int k = 0; k < NBUCK; ++k) {
    s += ws[k * 128 + j];
    q += ws[k * 128 + 64 + j];
  }
  const float n = (float)(Bn * Ln);
  float mu = s / n;
  float var = q / n - mu * mu;
  ws[2048 + j] = mu;
  ws[2112 + j] = rsqrtf(var + kEps);
}

extern "C" void kernel_launch(void* const* d_in, const int* in_sizes, int n_in,
                              void* d_out, int out_size, void* d_ws,
                              size_t ws_size, hipStream_t stream) {
  const float* cand = (const float*)d_in[0];
  const float* clicks = (const float*)d_in[1];
  const int* mask = (const int*)d_in[2];
  const float* W1 = (const float*)d_in[3];
  const float* b1 = (const float*)d_in[4];
  const float* alpha = (const float*)d_in[5];
  const float* W2 = (const float*)d_in[6];
  const float* b2 = (const float*)d_in[7];
  float* out = (float*)d_out;
  float* ws = (float*)d_ws;

  hipMemsetAsync(d_ws, 0, NBUCK * 128 * sizeof(float), stream);
  din_kernel<0><<<Bn, 256, 0, stream>>>(cand, clicks, mask, W1, b1, alpha, W2,
                                        b2, ws, out);
  finalize_stats<<<1, 64, 0, stream>>>(ws);
  din_kernel<1><<<Bn, 256, 0, stream>>>(cand, clicks, mask, W1, b1, alpha, W2,
                                        b2, ws, out);
}

// Round 10
// 261.786 us; speedup vs baseline: 1.4313x; 1.1798x over previous
//
#include <hip/hip_runtime.h>

// DIN attention: B=4096, L=100, D=64 — MFMA fp16 2-term version.
// Factorized: h[b,l] = k_l @ M_b + cu_b, M_b[i][j] = V[i][j] + c_i*T[i][j]
//   V = W1[64:128]-W1[128:192], T = W1[192:256], cu = c@(W1[0:64]+W1[128:192]) + b1
// k, M cast to fp16 via hardware v_cvt_pkrtz (err ~2^-10 on products; final
// out err ~1e-3 vs 1.37e-2 threshold). Per block:
//   C[112x64] (rows 100..111 zero-padded) = A[112x64] @ B[64x64]
// via mfma_f32_16x16x32_f16; wave w owns col-tile w (cols 16w..16w+15).
//
// ws layout (floats):
//   [0,2048):    stat buckets [16][128] (sum[0:64], sumsq[64:128]) — zeroed each launch
//   [2048,2112): mu
//   [2112,2176): rsig = rsqrt(var + 1e-9)

constexpr int Bn = 4096;
constexpr int Ln = 100;
constexpr int LP = 112;  // padded rows (7 tiles of 16)
constexpr float kEps = 1e-9f;
constexpr int NBUCK = 16;

typedef _Float16 half8 __attribute__((ext_vector_type(8)));
typedef __attribute__((ext_vector_type(4))) float f32x4;

// Row-major fp16 tile, row stride 128B, XOR-swizzled (G4: breaks the
// 16-way conflict of stride-128B column reads). Same fn for write+read.
static __device__ __forceinline__ int swz(int row, int byteInRow) {
  return row * 128 + (byteInRow ^ ((row & 7) << 4));
}

template <int PHASE>
__global__ __launch_bounds__(256) void din_kernel(
    const float* __restrict__ cand, const float* __restrict__ clicks,
    const int* __restrict__ mask, const float* __restrict__ W1,
    const float* __restrict__ b1, const float* __restrict__ alpha,
    const float* __restrict__ W2, const float* __restrict__ b2,
    float* __restrict__ ws, float* __restrict__ out) {
  __shared__ alignas(16) _Float16 AS[LP * 64];   // clicks fp16, swizzled rows
  __shared__ alignas(16) _Float16 MS[64 * 64];   // M^T [j][i] fp16, swizzled
  __shared__ float cshS[64];
  __shared__ float cuS[64];
  __shared__ float scratchS[4][LP];  // cu partials / svp / out partials
  __shared__ float s_lds[LP];
  __shared__ float w_lds[LP];

  const int b = blockIdx.x;
  const int tid = threadIdx.x;
  const int lane = tid & 63;
  const int w = tid >> 6;

  if (tid < 64) cshS[tid] = cand[(size_t)b * 64 + tid];
  __syncthreads();

  // ---- Prologue A: build M^T fp16 + cu partials. thread: col j=lane,
  // i in [16w,16w+16) as 8 pairs (1 v_cvt_pkrtz per pair).
  {
    float cuacc = 0.f;
#pragma unroll
    for (int p = 0; p < 8; ++p) {
      const int i0 = w * 16 + p * 2;
      float m[2];
#pragma unroll
      for (int q = 0; q < 2; ++q) {
        const int i = i0 + q;
        const float ci = cshS[i];
        m[q] = W1[(64 + i) * 64 + lane] - W1[(128 + i) * 64 + lane] +
               ci * W1[(192 + i) * 64 + lane];
        cuacc = fmaf(ci, W1[i * 64 + lane] + W1[(128 + i) * 64 + lane], cuacc);
      }
      auto pk = __builtin_amdgcn_cvt_pkrtz(m[0], m[1]);
      *(decltype(pk)*)((char*)MS + swz(lane, i0 * 2)) = pk;
    }
    scratchS[w][lane] = cuacc;
  }

  // ---- Prologue B: clicks -> fp16 in LDS. Wave w: rows [28w,28w+28),
  // 2 rows/iter: lane covers (row = lane>>5, col pair = lane&31).
  {
    const float2* crow2 = (const float2*)(clicks + (size_t)b * Ln * 64);
    const int colh = lane & 31;
    const int rsel = lane >> 5;
#pragma unroll
    for (int it = 0; it < 14; ++it) {
      const int l = 28 * w + it * 2 + rsel;
      float v0 = 0.f, v1 = 0.f;
      if (l < Ln) {
        float2 v = crow2[l * 32 + colh];
        v0 = v.x;
        v1 = v.y;
      }
      auto pk = __builtin_amdgcn_cvt_pkrtz(v0, v1);
      *(decltype(pk)*)((char*)AS + swz(l, colh * 4)) = pk;
    }
  }
  __syncthreads();
  if (tid < 64)
    cuS[tid] = b1[tid] + scratchS[0][tid] + scratchS[1][tid] +
               scratchS[2][tid] + scratchS[3][tid];
  __syncthreads();

  // ---- MFMA phase. Wave w = col-tile w. Lane roles (16x16x32 f16):
  //   A: row = lane&15, k = (lane>>4)*8 + e ;  B: col = lane&15, same k
  //   D: col = lane&15, row = (lane>>4)*4 + r   [m89-verified]
  const int lo4 = lane & 15;
  const int hi2 = lane >> 4;
  const int bk2 = hi2 * 16;  // byte offset of this lane's 8-elem k chunk
  const int bcol = w * 16 + lo4;

  half8 B0 = *(const half8*)((char*)MS + swz(bcol, bk2));
  half8 B1 = *(const half8*)((char*)MS + swz(bcol, 64 + bk2));

  f32x4 acc[7];
#pragma unroll
  for (int rt = 0; rt < 7; ++rt) acc[rt] = (f32x4){0.f, 0.f, 0.f, 0.f};

#pragma unroll
  for (int rt = 0; rt < 7; ++rt) {
    const int arow = rt * 16 + lo4;
    half8 A0 = *(const half8*)((char*)AS + swz(arow, bk2));
    half8 A1 = *(const half8*)((char*)AS + swz(arow, 64 + bk2));
    f32x4 a = acc[rt];
    a = __builtin_amdgcn_mfma_f32_16x16x32_f16(A0, B0, a, 0, 0, 0);
    a = __builtin_amdgcn_mfma_f32_16x16x32_f16(A1, B1, a, 0, 0, 0);
    acc[rt] = a;
  }

  const int j = w * 16 + lo4;  // this lane's output column
  const float cuj = cuS[j];

  if (PHASE == 0) {
    // ---- Stats: column sums of h and h^2 over l<100.
    float ssum = 0.f, ssq = 0.f;
#pragma unroll
    for (int rt = 0; rt < 7; ++rt) {
#pragma unroll
      for (int r = 0; r < 4; ++r) {
        const int l = rt * 16 + hi2 * 4 + r;
        const float h = acc[rt][r] + cuj;
        if (l < Ln) {
          ssum += h;
          ssq = fmaf(h, h, ssq);
        }
      }
    }
    ssum += __shfl_xor(ssum, 16);
    ssum += __shfl_xor(ssum, 32);
    ssq += __shfl_xor(ssq, 16);
    ssq += __shfl_xor(ssq, 32);
    if (hi2 == 0) {
      atomicAdd(&ws[(b & (NBUCK - 1)) * 128 + j], ssum);
      atomicAdd(&ws[(b & (NBUCK - 1)) * 128 + 64 + j], ssq);
    }
  } else {
    // ---- Dice + logits.
    const float muj = ws[2048 + j];
    const float rsj = ws[2112 + j];
    const float aj = alpha[j];
    const float w2j = W2[j];
    const float b2v = b2[0];
#pragma unroll
    for (int rt = 0; rt < 7; ++rt) {
#pragma unroll
      for (int r = 0; r < 4; ++r) {
        const int l = rt * 16 + hi2 * 4 + r;
        const float h = acc[rt][r] + cuj;
        const float hn = (h - muj) * rsj;
        const float p = 1.f / (1.f + __expf(-hn));
        const float d = h * fmaf(p, 1.f - aj, aj);
        float sv = d * w2j;  // partial over this wave's 16 cols
        sv += __shfl_xor(sv, 1);
        sv += __shfl_xor(sv, 2);
        sv += __shfl_xor(sv, 4);
        sv += __shfl_xor(sv, 8);
        if (lo4 == 0) scratchS[w][l] = sv;
      }
    }
    __syncthreads();
    if (tid < LP)
      s_lds[tid] = b2v + scratchS[0][tid] + scratchS[1][tid] +
                   scratchS[2][tid] + scratchS[3][tid];
    __syncthreads();

    // ---- Masked softmax over L=100 (wave 0).
    if (w == 0) {
      const int* mrow = mask + (size_t)b * Ln;
      const bool has1 = (lane + 64) < Ln;
      float v0 = s_lds[lane];
      int m0 = mrow[lane];
      float v1 = has1 ? s_lds[lane + 64] : 0.f;
      int m1 = has1 ? mrow[lane + 64] : 0;
      float x0 = m0 ? v0 : -3.0e38f;
      float x1 = m1 ? v1 : -3.0e38f;
      float mx = fmaxf(x0, x1);
#pragma unroll
      for (int off = 32; off >= 1; off >>= 1) mx = fmaxf(mx, __shfl_xor(mx, off));
      float e0 = m0 ? __expf(v0 - mx) : 0.f;
      float e1 = m1 ? __expf(v1 - mx) : 0.f;
      float se = e0 + e1;
#pragma unroll
      for (int off = 32; off >= 1; off >>= 1) se += __shfl_xor(se, off);
      float inv = 1.f / se;
      w_lds[lane] = e0 * inv;
      if (has1) w_lds[lane + 64] = e1 * inv;
    }
    __syncthreads();

    // ---- out[b][j] = sum_l w_l * k[l][j], k from fp16 tile in LDS.
    float acco = 0.f;
#pragma unroll
    for (int t = 0; t < 25; ++t) {
      const int l = w + 4 * t;
      const float wl = w_lds[l];
      const _Float16 kv = *(const _Float16*)((char*)AS + swz(l, lane * 2));
      acco = fmaf(wl, (float)kv, acco);
    }
    scratchS[w][lane] = acco;
    __syncthreads();
    if (w == 0)
      out[(size_t)b * 64 + lane] = scratchS[0][lane] + scratchS[1][lane] +
                                   scratchS[2][lane] + scratchS[3][lane];
  }
}

__global__ void finalize_stats(float* __restrict__ ws) {
  int j = threadIdx.x;  // 64 threads
  float s = 0.f, q = 0.f;
#pragma unroll
  for (int k = 0; k < NBUCK; ++k) {
    s += ws[k * 128 + j];
    q += ws[k * 128 + 64 + j];
  }
  const float n = (float)(Bn * Ln);
  float mu = s / n;
  float var = q / n - mu * mu;
  ws[2048 + j] = mu;
  ws[2112 + j] = rsqrtf(var + kEps);
}

extern "C" void kernel_launch(void* const* d_in, const int* in_sizes, int n_in,
                              void* d_out, int out_size, void* d_ws,
                              size_t ws_size, hipStream_t stream) {
  const float* cand = (const float*)d_in[0];
  const float* clicks = (const float*)d_in[1];
  const int* mask = (const int*)d_in[2];
  const float* W1 = (const float*)d_in[3];
  const float* b1 = (const float*)d_in[4];
  const float* alpha = (const float*)d_in[5];
  const float* W2 = (const float*)d_in[6];
  const float* b2 = (const float*)d_in[7];
  float* out = (float*)d_out;
  float* ws = (float*)d_ws;

  (void)hipMemsetAsync(d_ws, 0, NBUCK * 128 * sizeof(float), stream);
  din_kernel<0><<<Bn, 256, 0, stream>>>(cand, clicks, mask, W1, b1, alpha, W2,
                                        b2, ws, out);
  finalize_stats<<<1, 64, 0, stream>>>(ws);
  din_kernel<1><<<Bn, 256, 0, stream>>>(cand, clicks, mask, W1, b1, alpha, W2,
                                        b2, ws, out);
}

// Round 11
// 236.085 us; speedup vs baseline: 1.5872x; 1.1089x over previous
//
#include <hip/hip_runtime.h>

// DIN attention: B=4096, L=100, D=64 — MFMA fp16, h materialized to ws.
// Factorized: h[b,l] = k_l @ M_b + cu_b, M_b[i][j] = V[i][j] + c_i*T[i][j]
//   V = W1[64:128]-W1[128:192], T = W1[192:256], cu = c@(W1[0:64]+W1[128:192]) + b1
// Phase0: build M/A fp16 tiles, MFMA h, global BN stats partials, store h~ (fp16)
// Phase1-lite: read h~, Dice+logits+softmax+weighted sum (clicks L3-warm).
// Fallback (ws too small): phase1 = full recompute (R10 behavior).
//
// ws layout (floats):
//   [0,2048):    stat buckets [16][128] (sum[0:64], sumsq[64:128]) — zeroed each launch
//   [2048,2112): mu
//   [2112,2176): rsig = rsqrt(var + 1e-9)
//   [2176, ...): h~ fp16 [B][100][64] (fast path only, 52.4 MB)

constexpr int Bn = 4096;
constexpr int Ln = 100;
constexpr int LP = 112;  // padded rows (7 tiles of 16)
constexpr float kEps = 1e-9f;
constexpr int NBUCK = 16;
constexpr size_t H_OFF_FLOATS = 2176;

typedef _Float16 half8 __attribute__((ext_vector_type(8)));
typedef __attribute__((ext_vector_type(4))) float f32x4;

// Row-major fp16 tile, row stride 128B, XOR-swizzled (G4: breaks the
// 16-way conflict of stride-128B column reads). Same fn for write+read.
static __device__ __forceinline__ int swz(int row, int byteInRow) {
  return row * 128 + (byteInRow ^ ((row & 7) << 4));
}

template <int PHASE, bool STOREH>
__global__ __launch_bounds__(256) void din_kernel(
    const float* __restrict__ cand, const float* __restrict__ clicks,
    const int* __restrict__ mask, const float* __restrict__ W1,
    const float* __restrict__ b1, const float* __restrict__ alpha,
    const float* __restrict__ W2, const float* __restrict__ b2,
    float* __restrict__ ws, _Float16* __restrict__ hbuf,
    float* __restrict__ out) {
  __shared__ alignas(16) _Float16 AS[LP * 64];   // clicks fp16, swizzled rows
  __shared__ alignas(16) _Float16 MS[64 * 64];   // M^T [j][i] fp16, swizzled
  __shared__ float cshS[64];
  __shared__ float cuS[64];
  __shared__ float scratchS[4][LP];  // cu partials / svp / out partials
  __shared__ float s_lds[LP];
  __shared__ float w_lds[LP];

  const int b = blockIdx.x;
  const int tid = threadIdx.x;
  const int lane = tid & 63;
  const int w = tid >> 6;

  if (tid < 64) cshS[tid] = cand[(size_t)b * 64 + tid];
  __syncthreads();

  // ---- Prologue A: build M^T fp16 + cu partials. thread: col j=lane,
  // i in [16w,16w+16) as 8 pairs (1 v_cvt_pkrtz per pair).
  {
    float cuacc = 0.f;
#pragma unroll
    for (int p = 0; p < 8; ++p) {
      const int i0 = w * 16 + p * 2;
      float m[2];
#pragma unroll
      for (int q = 0; q < 2; ++q) {
        const int i = i0 + q;
        const float ci = cshS[i];
        m[q] = W1[(64 + i) * 64 + lane] - W1[(128 + i) * 64 + lane] +
               ci * W1[(192 + i) * 64 + lane];
        cuacc = fmaf(ci, W1[i * 64 + lane] + W1[(128 + i) * 64 + lane], cuacc);
      }
      auto pk = __builtin_amdgcn_cvt_pkrtz(m[0], m[1]);
      *(decltype(pk)*)((char*)MS + swz(lane, i0 * 2)) = pk;
    }
    scratchS[w][lane] = cuacc;
  }

  // ---- Prologue B: clicks -> fp16 in LDS, float4 loads, 8B LDS writes.
  // 16 rows x 16 float4-chunks per iteration; 7 iterations cover 112 rows.
  {
    const float4* crow4 = (const float4*)(clicks + (size_t)b * Ln * 64);
    const int r16 = tid >> 4;  // row within group of 16
    const int c4 = tid & 15;   // float4 index in row
#pragma unroll
    for (int it = 0; it < 7; ++it) {
      const int l = it * 16 + r16;
      float4 v = {0.f, 0.f, 0.f, 0.f};
      if (l < Ln) v = crow4[l * 16 + c4];
      auto p0 = __builtin_amdgcn_cvt_pkrtz(v.x, v.y);
      auto p1 = __builtin_amdgcn_cvt_pkrtz(v.z, v.w);
      unsigned u0, u1;
      __builtin_memcpy(&u0, &p0, 4);
      __builtin_memcpy(&u1, &p1, 4);
      uint2 uv;
      uv.x = u0;
      uv.y = u1;
      *(uint2*)((char*)AS + swz(l, c4 * 8)) = uv;
    }
  }
  __syncthreads();
  if (tid < 64)
    cuS[tid] = b1[tid] + scratchS[0][tid] + scratchS[1][tid] +
               scratchS[2][tid] + scratchS[3][tid];
  __syncthreads();

  // ---- MFMA phase. Wave w = col-tile w. Lane roles (16x16x32 f16):
  //   A: row = lane&15, k = (lane>>4)*8 + e ;  B: col = lane&15, same k
  //   D: col = lane&15, row = (lane>>4)*4 + r   [m89-verified]
  const int lo4 = lane & 15;
  const int hi2 = lane >> 4;
  const int bk2 = hi2 * 16;  // byte offset of this lane's 8-elem k chunk
  const int bcol = w * 16 + lo4;

  half8 B0 = *(const half8*)((char*)MS + swz(bcol, bk2));
  half8 B1 = *(const half8*)((char*)MS + swz(bcol, 64 + bk2));

  f32x4 acc[7];
#pragma unroll
  for (int rt = 0; rt < 7; ++rt) acc[rt] = (f32x4){0.f, 0.f, 0.f, 0.f};

#pragma unroll
  for (int rt = 0; rt < 7; ++rt) {
    const int arow = rt * 16 + lo4;
    half8 A0 = *(const half8*)((char*)AS + swz(arow, bk2));
    half8 A1 = *(const half8*)((char*)AS + swz(arow, 64 + bk2));
    f32x4 a = acc[rt];
    a = __builtin_amdgcn_mfma_f32_16x16x32_f16(A0, B0, a, 0, 0, 0);
    a = __builtin_amdgcn_mfma_f32_16x16x32_f16(A1, B1, a, 0, 0, 0);
    acc[rt] = a;
  }

  const int j = w * 16 + lo4;  // this lane's output column
  const float cuj = cuS[j];

  if (PHASE == 0) {
    // ---- Stats: column sums of h and h^2 over l<100; optional h~ store.
    _Float16* hb = hbuf + (size_t)b * Ln * 64 + j;
    float ssum = 0.f, ssq = 0.f;
#pragma unroll
    for (int rt = 0; rt < 7; ++rt) {
#pragma unroll
      for (int r = 0; r < 4; ++r) {
        const int l = rt * 16 + hi2 * 4 + r;
        const float h = acc[rt][r] + cuj;
        if (l < Ln) {
          ssum += h;
          ssq = fmaf(h, h, ssq);
          if (STOREH) hb[(size_t)l * 64] = (_Float16)h;
        }
      }
    }
    ssum += __shfl_xor(ssum, 16);
    ssum += __shfl_xor(ssum, 32);
    ssq += __shfl_xor(ssq, 16);
    ssq += __shfl_xor(ssq, 32);
    if (hi2 == 0) {
      atomicAdd(&ws[(b & (NBUCK - 1)) * 128 + j], ssum);
      atomicAdd(&ws[(b & (NBUCK - 1)) * 128 + 64 + j], ssq);
    }
  } else {
    // ---- Dice + logits (fallback full recompute path).
    const float muj = ws[2048 + j];
    const float rsj = ws[2112 + j];
    const float aj = alpha[j];
    const float w2j = W2[j];
    const float b2v = b2[0];
#pragma unroll
    for (int rt = 0; rt < 7; ++rt) {
#pragma unroll
      for (int r = 0; r < 4; ++r) {
        const int l = rt * 16 + hi2 * 4 + r;
        const float h = acc[rt][r] + cuj;
        const float hn = (h - muj) * rsj;
        const float p = 1.f / (1.f + __expf(-hn));
        const float d = h * fmaf(p, 1.f - aj, aj);
        float sv = d * w2j;  // partial over this wave's 16 cols
        sv += __shfl_xor(sv, 1);
        sv += __shfl_xor(sv, 2);
        sv += __shfl_xor(sv, 4);
        sv += __shfl_xor(sv, 8);
        if (lo4 == 0) scratchS[w][l] = sv;
      }
    }
    __syncthreads();
    if (tid < LP)
      s_lds[tid] = b2v + scratchS[0][tid] + scratchS[1][tid] +
                   scratchS[2][tid] + scratchS[3][tid];
    __syncthreads();

    // ---- Masked softmax over L=100 (wave 0).
    if (w == 0) {
      const int* mrow = mask + (size_t)b * Ln;
      const bool has1 = (lane + 64) < Ln;
      float v0 = s_lds[lane];
      int m0 = mrow[lane];
      float v1 = has1 ? s_lds[lane + 64] : 0.f;
      int m1 = has1 ? mrow[lane + 64] : 0;
      float x0 = m0 ? v0 : -3.0e38f;
      float x1 = m1 ? v1 : -3.0e38f;
      float mx = fmaxf(x0, x1);
#pragma unroll
      for (int off = 32; off >= 1; off >>= 1) mx = fmaxf(mx, __shfl_xor(mx, off));
      float e0 = m0 ? __expf(v0 - mx) : 0.f;
      float e1 = m1 ? __expf(v1 - mx) : 0.f;
      float se = e0 + e1;
#pragma unroll
      for (int off = 32; off >= 1; off >>= 1) se += __shfl_xor(se, off);
      float inv = 1.f / se;
      w_lds[lane] = e0 * inv;
      if (has1) w_lds[lane + 64] = e1 * inv;
    }
    __syncthreads();

    // ---- out[b][j] = sum_l w_l * k[l][j], k from fp16 tile in LDS.
    float acco = 0.f;
#pragma unroll
    for (int t = 0; t < 25; ++t) {
      const int l = w + 4 * t;
      const float wl = w_lds[l];
      const _Float16 kv = *(const _Float16*)((char*)AS + swz(l, lane * 2));
      acco = fmaf(wl, (float)kv, acco);
    }
    scratchS[w][lane] = acco;
    __syncthreads();
    if (w == 0)
      out[(size_t)b * 64 + lane] = scratchS[0][lane] + scratchS[1][lane] +
                                   scratchS[2][lane] + scratchS[3][lane];
  }
}

// Lite phase1: h~ from ws, no staging, no MFMA. ~1.9 KB LDS.
__global__ __launch_bounds__(256) void din_lite(
    const float* __restrict__ clicks, const int* __restrict__ mask,
    const float* __restrict__ alpha, const float* __restrict__ W2,
    const float* __restrict__ b2, const float* __restrict__ ws,
    const _Float16* __restrict__ hbuf, float* __restrict__ out) {
  __shared__ float s_lds[LP];
  __shared__ float w_lds[Ln];
  __shared__ float scratchS[4][64];

  const int b = blockIdx.x;
  const int tid = threadIdx.x;
  const int lane = tid & 63;
  const int w = tid >> 6;

  const float muj = ws[2048 + lane];
  const float rsj = ws[2112 + lane];
  const float aj = alpha[lane];
  const float w2j = W2[lane];
  const float b2v = b2[0];

  const _Float16* hrow = hbuf + (size_t)b * Ln * 64 + lane;

  // Dice + logits: wave w handles l = w + 4t; full-wave 64-lane reduce.
#pragma unroll 5
  for (int t = 0; t < 25; ++t) {
    const int l = w + 4 * t;
    const float h = (float)hrow[(size_t)l * 64];
    const float hn = (h - muj) * rsj;
    const float p = 1.f / (1.f + __expf(-hn));
    const float d = h * fmaf(p, 1.f - aj, aj);
    float sv = d * w2j;
#pragma unroll
    for (int off = 32; off >= 1; off >>= 1) sv += __shfl_xor(sv, off);
    if (lane == 0) s_lds[l] = sv + b2v;
  }
  __syncthreads();

  // Masked softmax over L=100 (wave 0).
  if (w == 0) {
    const int* mrow = mask + (size_t)b * Ln;
    const bool has1 = (lane + 64) < Ln;
    float v0 = s_lds[lane];
    int m0 = mrow[lane];
    float v1 = has1 ? s_lds[lane + 64] : 0.f;
    int m1 = has1 ? mrow[lane + 64] : 0;
    float x0 = m0 ? v0 : -3.0e38f;
    float x1 = m1 ? v1 : -3.0e38f;
    float mx = fmaxf(x0, x1);
#pragma unroll
    for (int off = 32; off >= 1; off >>= 1) mx = fmaxf(mx, __shfl_xor(mx, off));
    float e0 = m0 ? __expf(v0 - mx) : 0.f;
    float e1 = m1 ? __expf(v1 - mx) : 0.f;
    float se = e0 + e1;
#pragma unroll
    for (int off = 32; off >= 1; off >>= 1) se += __shfl_xor(se, off);
    float inv = 1.f / se;
    w_lds[lane] = e0 * inv;
    if (has1) w_lds[lane + 64] = e1 * inv;
  }
  __syncthreads();

  // out[b][j] = sum_l w_l * clicks[b][l][j] (clicks L3-warm from phase0).
  const float* crow = clicks + (size_t)b * Ln * 64;
  float acco = 0.f;
#pragma unroll 5
  for (int t = 0; t < 25; ++t) {
    const int l = w + 4 * t;
    acco = fmaf(w_lds[l], crow[(size_t)l * 64 + lane], acco);
  }
  scratchS[w][lane] = acco;
  __syncthreads();
  if (w == 0)
    out[(size_t)b * 64 + lane] = scratchS[0][lane] + scratchS[1][lane] +
                                 scratchS[2][lane] + scratchS[3][lane];
}

__global__ void finalize_stats(float* __restrict__ ws) {
  int j = threadIdx.x;  // 64 threads
  float s = 0.f, q = 0.f;
#pragma unroll
  for (int k = 0; k < NBUCK; ++k) {
    s += ws[k * 128 + j];
    q += ws[k * 128 + 64 + j];
  }
  const float n = (float)(Bn * Ln);
  float mu = s / n;
  float var = q / n - mu * mu;
  ws[2048 + j] = mu;
  ws[2112 + j] = rsqrtf(var + kEps);
}

extern "C" void kernel_launch(void* const* d_in, const int* in_sizes, int n_in,
                              void* d_out, int out_size, void* d_ws,
                              size_t ws_size, hipStream_t stream) {
  const float* cand = (const float*)d_in[0];
  const float* clicks = (const float*)d_in[1];
  const int* mask = (const int*)d_in[2];
  const float* W1 = (const float*)d_in[3];
  const float* b1 = (const float*)d_in[4];
  const float* alpha = (const float*)d_in[5];
  const float* W2 = (const float*)d_in[6];
  const float* b2 = (const float*)d_in[7];
  float* out = (float*)d_out;
  float* ws = (float*)d_ws;
  _Float16* hbuf = (_Float16*)(ws + H_OFF_FLOATS);

  const size_t need =
      H_OFF_FLOATS * sizeof(float) + (size_t)Bn * Ln * 64 * sizeof(_Float16);
  const bool fast = ws_size >= need;

  (void)hipMemsetAsync(d_ws, 0, NBUCK * 128 * sizeof(float), stream);
  if (fast) {
    din_kernel<0, true><<<Bn, 256, 0, stream>>>(cand, clicks, mask, W1, b1,
                                                alpha, W2, b2, ws, hbuf, out);
    finalize_stats<<<1, 64, 0, stream>>>(ws);
    din_lite<<<Bn, 256, 0, stream>>>(clicks, mask, alpha, W2, b2, ws, hbuf,
                                     out);
  } else {
    din_kernel<0, false><<<Bn, 256, 0, stream>>>(cand, clicks, mask, W1, b1,
                                                 alpha, W2, b2, ws, hbuf, out);
    finalize_stats<<<1, 64, 0, stream>>>(ws);
    din_kernel<1, false><<<Bn, 256, 0, stream>>>(cand, clicks, mask, W1, b1,
                                                 alpha, W2, b2, ws, hbuf, out);
  }
}